// Round 17
// baseline (164.148 us; speedup 1.0000x reference)
//
#include <hip/hip_runtime.h>
#include <hip/hip_bf16.h>
#include <math.h>

// ---------------- problem constants ----------------
#define BATCH 65536
#define NT 512
#define BM 16

using f32x4 = __attribute__((ext_vector_type(4))) float;
using s16x8 = __attribute__((ext_vector_type(8))) short;

#define MFMA16(a, b, c) __builtin_amdgcn_mfma_f32_16x16x32_bf16((a), (b), (c), 0, 0, 0)

__device__ __forceinline__ unsigned short f2bf(float f) {
    unsigned u = __builtin_bit_cast(unsigned, f);
    u = u + 0x7FFFu + ((u >> 16) & 1u);   // RNE
    return (unsigned short)(u >> 16);
}

// A&S 7.1.26 erf, branchless, err 1.5e-7
__device__ __forceinline__ float fast_erf(float x) {
    float ax = fabsf(x);
    float t = __builtin_amdgcn_rcpf(fmaf(0.3275911f, ax, 1.0f));
    float poly = t * fmaf(t, fmaf(t, fmaf(t, fmaf(t, 1.061405429f, -1.453152027f),
                                          1.421413741f), -0.284496736f), 0.254829592f);
    float r = 1.0f - poly * __expf(-ax * ax);
    return copysignf(r, x);
}
__device__ __forceinline__ float gelu(float y) {
    return 0.5f * y * (1.0f + fast_erf(y * 0.70710678118654752f));
}

// swizzled LDS addressing: HBUF rows 1024B; 16B granule XOR (row&7)
__device__ __forceinline__ int hswz(int row, int k) {
    return row * 1024 + ((((k >> 3) ^ (row & 7))) << 4) + ((k & 7) << 1);
}

// ---------------- weights prep: fragment-linearized bf16 layout ----------------
// frag(nt, ks) element(lane, e) = W[k = ks*32 + (lane>>4)*8 + e][n = nt*16 + (lane&15)]
// dst[(fragidx*64 + lane)*8 + e]  -> one 1KB coalesced block per fragment.
__global__ void weights_frag(const float* __restrict__ W1, const float* __restrict__ W2,
                             const float* __restrict__ W3, unsigned short* __restrict__ wt) {
    int b = blockIdx.x;
    int lane = threadIdx.x;                 // 64 threads
    const float* src; unsigned short* dst; int N, fragidx;
    if (b < 64)       { src = W1; dst = wt;          N = 512; fragidx = b; }
    else if (b < 576) { src = W2; dst = wt + 32768;  N = 512; fragidx = b - 64; }
    else              { src = W3; dst = wt + 294912; N = 64;  fragidx = b - 576; }
    int nt, ks;
    if (b < 64) { nt = fragidx >> 1; ks = fragidx & 1; }
    else        { nt = fragidx >> 4; ks = fragidx & 15; }
    int n  = nt * 16 + (lane & 15);
    int k0 = ks * 32 + (lane >> 4) * 8;
    unsigned short o[8];
#pragma unroll
    for (int e = 0; e < 8; e++) o[e] = f2bf(src[(size_t)(k0 + e) * N + n]);
    *(uint4*)(dst + ((size_t)fragidx * 64 + lane) * 8) = *(uint4*)o;
}

// =========================================================================
// K123 BM=16: GEMM1+LN1+GELU -> GEMM2+LN2+GELU -> GEMM3(+parallel a-stage)
//             -> softmax -> conv. acc[1][4] = 16 AGPR -> fits (512,6) cap 85.
// LDS (no overlay): HBUF 16KB @0 | XB @16384 (2KB) | RB @18432 (1KB) |
//                   SB @19456 (128B) | LOGB @19584 (4.25KB) | APAD @23936 (8.5KB)
// =========================================================================
#define XB 16384
#define RB 18432
#define SB 19456
#define LOGB 19584
#define APAD 23936
#define LST 272
#define AST 544
#define SMEM_K 32640
__global__ __launch_bounds__(NT, 6) void k123_fused(
    const float* __restrict__ shift_bits, const float* __restrict__ a_bits,
    const float* __restrict__ b1, const float* __restrict__ g1, const float* __restrict__ be1,
    const float* __restrict__ b2, const float* __restrict__ g2, const float* __restrict__ be2,
    const float* __restrict__ b3, const unsigned short* __restrict__ wt,
    float* __restrict__ out) {
    __shared__ char smem[SMEM_K];
    const int t = threadIdx.x;
    const int wave = t >> 6, lane = t & 63, g = lane >> 4, ln = lane & 15;
    const int row0 = blockIdx.x * BM;
    const int n0w = wave * 64;

    // ---- stage shift_bits (16x64 f32 -> bf16, swizzled): 2 elems/thread ----
    {
        int r = t >> 5, c2 = (t & 31) * 2;
        float2 x = *(const float2*)(shift_bits + (size_t)(row0 + r) * 64 + c2);
        unsigned p = (unsigned)f2bf(x.x) | ((unsigned)f2bf(x.y) << 16);
        *(unsigned*)(smem + XB + r * 128 + (((c2 >> 3) ^ (r & 7)) << 4) + ((c2 & 7) << 1)) = p;
    }
    __syncthreads();

    // ---- GEMM1: x(16x64) @ W1(64x512) -> acc[4] (wave's 64 cols) ----
    const unsigned short* w1base = wt + ((size_t)wave * 8 * 64 + lane) * 8;
    f32x4 acc[4];
#pragma unroll
    for (int fn = 0; fn < 4; fn++) acc[fn] = (f32x4){0.f, 0.f, 0.f, 0.f};
#pragma unroll
    for (int ks = 0; ks < 2; ks++) {
        s16x8 bf[4];
#pragma unroll
        for (int fn = 0; fn < 4; fn++)
            bf[fn] = *(const s16x8*)(w1base + (size_t)(fn * 2 + ks) * 512);
        s16x8 af = *(const s16x8*)(smem + XB + ln * 128 +
                                   ((((ks * 32 + g * 8) >> 3) ^ (ln & 7)) << 4) +
                                   (((ks * 32 + g * 8) & 7) << 1));
#pragma unroll
        for (int fn = 0; fn < 4; fn++) acc[fn] = MFMA16(af, bf[fn], acc[fn]);
    }

    // ---- LN1: bias + partials -> stats ----
    {
        float bb[4];
#pragma unroll
        for (int fn = 0; fn < 4; fn++) bb[fn] = b1[n0w + fn * 16 + ln];
#pragma unroll
        for (int fn = 0; fn < 4; fn++)
#pragma unroll
            for (int r = 0; r < 4; r++) acc[fn][r] += bb[fn];
#pragma unroll
        for (int r = 0; r < 4; r++) {
            float s = 0.f, q = 0.f;
#pragma unroll
            for (int fn = 0; fn < 4; fn++) { float v = acc[fn][r]; s += v; q += v * v; }
#pragma unroll
            for (int m = 1; m < 16; m <<= 1) { s += __shfl_xor(s, m, 64); q += __shfl_xor(q, m, 64); }
            if (ln == 0) {
                int row = g * 4 + r;
                float* rp = (float*)(smem + RB + (row * 8 + wave) * 8);
                rp[0] = s; rp[1] = q;
            }
        }
    }
    __syncthreads();
    if (t < 16) {
        float s = 0.f, q = 0.f;
#pragma unroll
        for (int w = 0; w < 8; w++) {
            float* rp = (float*)(smem + RB + (t * 8 + w) * 8);
            s += rp[0]; q += rp[1];
        }
        float mu = s * (1.0f / 512.0f);
        float var = q * (1.0f / 512.0f) - mu * mu;
        float rs = rsqrtf(var + 1e-5f);
        float* sp = (float*)(smem + SB + t * 8);
        sp[0] = mu; sp[1] = rs;
    }
    __syncthreads();
    // LN1 apply + GELU -> HBUF
    {
        float gm[4], bt[4];
#pragma unroll
        for (int fn = 0; fn < 4; fn++) { int c = n0w + fn * 16 + ln; gm[fn] = g1[c]; bt[fn] = be1[c]; }
#pragma unroll
        for (int r = 0; r < 4; r++) {
            int row = g * 4 + r;
            float* sp = (float*)(smem + SB + row * 8);
            float mu = sp[0], rs = sp[1];
#pragma unroll
            for (int fn = 0; fn < 4; fn++) {
                int col = n0w + fn * 16 + ln;
                float y = (acc[fn][r] - mu) * rs * gm[fn] + bt[fn];
                *(unsigned short*)(smem + hswz(row, col)) = f2bf(gelu(y));
            }
        }
    }
    __syncthreads();

    // ---- GEMM2: h1(16x512) @ W2, coalesced frag loads ----
    const unsigned short* w2base = wt + 32768 + ((size_t)wave * 64 * 64 + lane) * 8;
#pragma unroll
    for (int fn = 0; fn < 4; fn++) acc[fn] = (f32x4){0.f, 0.f, 0.f, 0.f};
#pragma unroll
    for (int step = 0; step < 16; step++) {
        s16x8 bf[4];
#pragma unroll
        for (int fn = 0; fn < 4; fn++)
            bf[fn] = *(const s16x8*)(w2base + (size_t)(fn * 16 + step) * 512);
        s16x8 af = *(const s16x8*)(smem + hswz(ln, step * 32 + g * 8));
#pragma unroll
        for (int fn = 0; fn < 4; fn++) acc[fn] = MFMA16(af, bf[fn], acc[fn]);
    }

    // ---- LN2: bias + partials -> stats ----
    {
        float bb[4];
#pragma unroll
        for (int fn = 0; fn < 4; fn++) bb[fn] = b2[n0w + fn * 16 + ln];
#pragma unroll
        for (int fn = 0; fn < 4; fn++)
#pragma unroll
            for (int r = 0; r < 4; r++) acc[fn][r] += bb[fn];
#pragma unroll
        for (int r = 0; r < 4; r++) {
            float s = 0.f, q = 0.f;
#pragma unroll
            for (int fn = 0; fn < 4; fn++) { float v = acc[fn][r]; s += v; q += v * v; }
#pragma unroll
            for (int m = 1; m < 16; m <<= 1) { s += __shfl_xor(s, m, 64); q += __shfl_xor(q, m, 64); }
            if (ln == 0) {
                int row = g * 4 + r;
                float* rp = (float*)(smem + RB + (row * 8 + wave) * 8);
                rp[0] = s; rp[1] = q;
            }
        }
    }
    __syncthreads();
    if (t < 16) {
        float s = 0.f, q = 0.f;
#pragma unroll
        for (int w = 0; w < 8; w++) {
            float* rp = (float*)(smem + RB + (t * 8 + w) * 8);
            s += rp[0]; q += rp[1];
        }
        float mu = s * (1.0f / 512.0f);
        float var = q * (1.0f / 512.0f) - mu * mu;
        float rs = rsqrtf(var + 1e-5f);
        float* sp = (float*)(smem + SB + t * 8);
        sp[0] = mu; sp[1] = rs;
    }
    __syncthreads();
    // LN2 apply + GELU -> HBUF (h2 only in LDS)
    {
        float gm[4], bt[4];
#pragma unroll
        for (int fn = 0; fn < 4; fn++) { int c = n0w + fn * 16 + ln; gm[fn] = g2[c]; bt[fn] = be2[c]; }
#pragma unroll
        for (int r = 0; r < 4; r++) {
            int row = g * 4 + r;
            float* sp = (float*)(smem + SB + row * 8);
            float mu = sp[0], rs = sp[1];
#pragma unroll
            for (int fn = 0; fn < 4; fn++) {
                int col = n0w + fn * 16 + ln;
                float y = (acc[fn][r] - mu) * rs * gm[fn] + bt[fn];
                *(unsigned short*)(smem + hswz(row, col)) = f2bf(gelu(y));
            }
        }
    }
    __syncthreads();

    // ---- GEMM3 (waves 0-3) in parallel with a_bits staging (waves 4-7) ----
    if (wave < 4) {
        const int q = wave;
        float b3v = b3[q * 16 + ln];
        const unsigned short* b3p = wt + 294912 + ((size_t)q * 16 * 64 + lane) * 8;
        f32x4 acc3a = (f32x4){0.f, 0.f, 0.f, 0.f};
        f32x4 acc3b = (f32x4){0.f, 0.f, 0.f, 0.f};
#pragma unroll
        for (int ks = 0; ks < 16; ks += 2) {
            s16x8 bfr0 = *(const s16x8*)(b3p + (size_t)ks * 512);
            s16x8 bfr1 = *(const s16x8*)(b3p + (size_t)(ks + 1) * 512);
            s16x8 af0 = *(const s16x8*)(smem + hswz(ln, ks * 32 + g * 8));
            s16x8 af1 = *(const s16x8*)(smem + hswz(ln, (ks + 1) * 32 + g * 8));
            acc3a = MFMA16(af0, bfr0, acc3a);
            acc3b = MFMA16(af1, bfr1, acc3b);
        }
        // logits (+b3) -> LOGB (separate region; no barrier needed before write)
#pragma unroll
        for (int r = 0; r < 4; r++) {
            int row = g * 4 + r;
            *(float*)(smem + LOGB + row * LST + (q * 16 + ln) * 4) = acc3a[r] + acc3b[r] + b3v;
        }
    } else {
        // zero-padded a-tile into APAD
        int idx = t - 256;
        int r = idx >> 4, c0 = (idx & 15) * 4;
        float* ap = (float*)(smem + APAD + r * AST);
        float4 z4 = {0.f, 0.f, 0.f, 0.f};
        *(float4*)(ap + c0) = z4;
        float4 av = *(const float4*)(a_bits + (size_t)(row0 + r) * 64 + c0);
        *(float4*)(ap + 64 + c0) = av;
    }
    __syncthreads();

    // ---- softmax over 64 (16 thr/row, threads 0-255) ----
    if (t < 256) {
        int r = t >> 4, c0 = (t & 15) * 4;
        float* lp = (float*)(smem + LOGB + r * LST + c0 * 4);
        float4 v = *(float4*)lp;
        float mx = fmaxf(fmaxf(v.x, v.y), fmaxf(v.z, v.w));
#pragma unroll
        for (int d = 1; d < 16; d <<= 1) mx = fmaxf(mx, __shfl_xor(mx, d, 64));
        float e0 = __expf(v.x - mx), e1 = __expf(v.y - mx);
        float e2 = __expf(v.z - mx), e3 = __expf(v.w - mx);
        float s = e0 + e1 + e2 + e3;
#pragma unroll
        for (int d = 1; d < 16; d <<= 1) s += __shfl_xor(s, d, 64);
        float inv = 1.0f / s;
        float4 o; o.x = e0 * inv; o.y = e1 * inv; o.z = e2 * inv; o.w = e3 * inv;
        *(float4*)lp = o;
    }
    __syncthreads();

    // ---- causal conv (threads 0-255): 16 thr/row, 4 outs/thread ----
    if (t < 256) {
        int r = t >> 4, i0 = (t & 15) * 4;
        const float* prow = (const float*)(smem + LOGB + r * LST);
        const float* apad = (const float*)(smem + APAD + r * AST);
        float W[8];
        {
            float4 wa = *(const float4*)(apad + i0 + 60);
            float4 wb = *(const float4*)(apad + i0 + 64);
            W[0] = wa.x; W[1] = wa.y; W[2] = wa.z; W[3] = wa.w;
            W[4] = wb.x; W[5] = wb.y; W[6] = wb.z; W[7] = wb.w;
        }
        float o0 = 0.f, o1 = 0.f, o2 = 0.f, o3 = 0.f;
#pragma unroll
        for (int s4 = 0; s4 < 16; s4++) {
            float4 p4 = *(const float4*)(prow + 4 * s4);
            o0 = fmaf(p4.x, W[4], fmaf(p4.y, W[3], fmaf(p4.z, W[2], fmaf(p4.w, W[1], o0))));
            o1 = fmaf(p4.x, W[5], fmaf(p4.y, W[4], fmaf(p4.z, W[3], fmaf(p4.w, W[2], o1))));
            o2 = fmaf(p4.x, W[6], fmaf(p4.y, W[5], fmaf(p4.z, W[4], fmaf(p4.w, W[3], o2))));
            o3 = fmaf(p4.x, W[7], fmaf(p4.y, W[6], fmaf(p4.z, W[5], fmaf(p4.w, W[4], o3))));
            if (s4 < 15) {
                W[4] = W[0]; W[5] = W[1]; W[6] = W[2]; W[7] = W[3];
                float4 nw = *(const float4*)(apad + i0 + 56 - 4 * s4);
                W[0] = nw.x; W[1] = nw.y; W[2] = nw.z; W[3] = nw.w;
            }
        }
        float4 o; o.x = o0; o.y = o1; o.z = o2; o.w = o3;
        *(float4*)(out + (size_t)(row0 + r) * 64 + i0) = o;
    }
}

extern "C" void kernel_launch(void* const* d_in, const int* in_sizes, int n_in,
                              void* d_out, int out_size, void* d_ws, size_t ws_size,
                              hipStream_t stream) {
    const float* a_bits = (const float*)d_in[0];
    const float* shift  = (const float*)d_in[1];
    const float* W1  = (const float*)d_in[2];
    const float* b1  = (const float*)d_in[3];
    const float* g1  = (const float*)d_in[4];
    const float* be1 = (const float*)d_in[5];
    const float* W2  = (const float*)d_in[6];
    const float* b2  = (const float*)d_in[7];
    const float* g2  = (const float*)d_in[8];
    const float* be2 = (const float*)d_in[9];
    const float* W3  = (const float*)d_in[10];
    const float* b3  = (const float*)d_in[11];
    float* out = (float*)d_out;
    unsigned short* wt = (unsigned short*)d_ws;

    weights_frag<<<640, 64, 0, stream>>>(W1, W2, W3, wt);
    k123_fused<<<BATCH / BM, NT, 0, stream>>>(shift, a_bits, b1, g1, be1,
                                              b2, g2, be2, b3, wt, out);
}

// Round 18
// 140.485 us; speedup vs baseline: 1.1684x; 1.1684x over previous
//
#include <hip/hip_runtime.h>
#include <hip/hip_bf16.h>
#include <math.h>

// ---------------- problem constants ----------------
#define BATCH 65536
#define NT 512
#define BM 32

using f32x4 = __attribute__((ext_vector_type(4))) float;
using s16x8 = __attribute__((ext_vector_type(8))) short;

#define MFMA16(a, b, c) __builtin_amdgcn_mfma_f32_16x16x32_bf16((a), (b), (c), 0, 0, 0)

__device__ __forceinline__ unsigned short f2bf(float f) {
    unsigned u = __builtin_bit_cast(unsigned, f);
    u = u + 0x7FFFu + ((u >> 16) & 1u);   // RNE
    return (unsigned short)(u >> 16);
}

// tanh-form GELU: 0.5x(1+tanh(0.79788456(x+0.044715x^3))), ~8 VALU ops.
// tanh(z) = 1 - 2/(exp(2z)+1); inf-safe at both tails. Max abs dev from
// exact-erf GELU ~1e-3 < bf16 grain of h (0.0078 @ |h|=1).
__device__ __forceinline__ float gelu(float x) {
    float x2 = x * x;
    float z = x * fmaf(x2, 0.0356774081f, 0.7978845608f);   // c0*(x + c1 x^3)
    float e = __expf(z + z);
    float r = __builtin_amdgcn_rcpf(e + 1.0f);
    float th = fmaf(-2.0f, r, 1.0f);
    return 0.5f * x * (1.0f + th);
}

// swizzled LDS addressing: HBUF rows 1024B; 16B granule XOR (row&7)
__device__ __forceinline__ int hswz(int row, int k) {
    return row * 1024 + ((((k >> 3) ^ (row & 7))) << 4) + ((k & 7) << 1);
}
__device__ __forceinline__ int xaddr(int base, int row, int k) {
    return base + row * 128 + ((((k >> 3) ^ (row & 7))) << 4) + ((k & 7) << 1);
}

// ---------------- weights prep: fragment-linearized bf16 layout ----------------
// frag(nt, ks) element(lane, e) = W[k = ks*32 + (lane>>4)*8 + e][n = nt*16 + (lane&15)]
// dst[(fragidx*64 + lane)*8 + e]  -> one 1KB coalesced block per fragment.
__global__ void weights_frag(const float* __restrict__ W1, const float* __restrict__ W2,
                             const float* __restrict__ W3, unsigned short* __restrict__ wt) {
    int b = blockIdx.x;
    int lane = threadIdx.x;                 // 64 threads
    const float* src; unsigned short* dst; int N, fragidx;
    if (b < 64)       { src = W1; dst = wt;          N = 512; fragidx = b; }
    else if (b < 576) { src = W2; dst = wt + 32768;  N = 512; fragidx = b - 64; }
    else              { src = W3; dst = wt + 294912; N = 64;  fragidx = b - 576; }
    int nt, ks;
    if (b < 64) { nt = fragidx >> 1; ks = fragidx & 1; }
    else        { nt = fragidx >> 4; ks = fragidx & 15; }
    int n  = nt * 16 + (lane & 15);
    int k0 = ks * 32 + (lane >> 4) * 8;
    unsigned short o[8];
#pragma unroll
    for (int e = 0; e < 8; e++) o[e] = f2bf(src[(size_t)(k0 + e) * N + n]);
    *(uint4*)(dst + ((size_t)fragidx * 64 + lane) * 8) = *(uint4*)o;
}

// ---------------- shared LN partial helper (8 waves) ----------------
__device__ __forceinline__ void ln_partials(f32x4 (&acc)[2][4], char* smem, int redb,
                                            int ln, int g, int wave) {
#pragma unroll
    for (int fm = 0; fm < 2; fm++)
#pragma unroll
        for (int r = 0; r < 4; r++) {
            float s = 0.f, q = 0.f;
#pragma unroll
            for (int fn = 0; fn < 4; fn++) { float v = acc[fm][fn][r]; s += v; q += v * v; }
#pragma unroll
            for (int m = 1; m < 16; m <<= 1) { s += __shfl_xor(s, m, 64); q += __shfl_xor(q, m, 64); }
            if (ln == 0) {
                int row = fm * 16 + g * 4 + r;
                float* rp = (float*)(smem + redb + (row * 8 + wave) * 8);
                rp[0] = s; rp[1] = q;
            }
        }
}

// =========================================================================
// K1: GEMM1 + LN1 + GELU -> h1 (bf16 row-major [rows][512])
// =========================================================================
#define SMEM_K1 39168
__global__ __launch_bounds__(NT, 6) void k1_gemm1(
    const float* __restrict__ shift_bits,
    const float* __restrict__ b1, const float* __restrict__ g1, const float* __restrict__ be1,
    const unsigned short* __restrict__ wt, unsigned short* __restrict__ h1,
    int rowoff) {
    __shared__ char smem[SMEM_K1];
    const int t = threadIdx.x;
    const int wave = t >> 6, lane = t & 63, g = lane >> 4, ln = lane & 15;
    const int row0 = rowoff + blockIdx.x * BM;
    const int lrow0 = blockIdx.x * BM;
    const int n0w = wave * 64;
    const int XB = 32768, RB = 36864, SB = 38912;
    const unsigned short* wt1f = wt;

    // stage shift_bits (32x64 f32 -> bf16 swizzled 128B rows)
    {
        int r = t >> 4, c = t & 15;
        float4 x = *(const float4*)(shift_bits + (size_t)(row0 + r) * 64 + c * 4);
        unsigned p0 = (unsigned)f2bf(x.x) | ((unsigned)f2bf(x.y) << 16);
        unsigned p1 = (unsigned)f2bf(x.z) | ((unsigned)f2bf(x.w) << 16);
        uint2 v; v.x = p0; v.y = p1;
        *(uint2*)(smem + XB + r * 128 + (((c >> 1) ^ (r & 7)) << 4) + (c & 1) * 8) = v;
    }
    __syncthreads();

    f32x4 acc[2][4];
#pragma unroll
    for (int fm = 0; fm < 2; fm++)
#pragma unroll
        for (int fn = 0; fn < 4; fn++) acc[fm][fn] = (f32x4){0.f, 0.f, 0.f, 0.f};
#pragma unroll
    for (int ks = 0; ks < 2; ks++) {
        s16x8 af[2], bf[4];
#pragma unroll
        for (int fn = 0; fn < 4; fn++) {
            int fragidx = (wave * 4 + fn) * 2 + ks;
            bf[fn] = *(const s16x8*)(wt1f + ((size_t)fragidx * 64 + lane) * 8);
        }
#pragma unroll
        for (int fm = 0; fm < 2; fm++)
            af[fm] = *(const s16x8*)(smem + xaddr(XB, fm * 16 + ln, ks * 32 + g * 8));
#pragma unroll
        for (int fm = 0; fm < 2; fm++)
#pragma unroll
            for (int fn = 0; fn < 4; fn++) acc[fm][fn] = MFMA16(af[fm], bf[fn], acc[fm][fn]);
    }

    {
        float bb[4];
#pragma unroll
        for (int fn = 0; fn < 4; fn++) bb[fn] = b1[n0w + fn * 16 + ln];
#pragma unroll
        for (int fm = 0; fm < 2; fm++)
#pragma unroll
            for (int fn = 0; fn < 4; fn++)
#pragma unroll
                for (int r = 0; r < 4; r++) acc[fm][fn][r] += bb[fn];
    }
    ln_partials(acc, smem, RB, ln, g, wave);
    __syncthreads();
    if (t < 32) {
        float s = 0.f, q = 0.f;
#pragma unroll
        for (int w = 0; w < 8; w++) {
            float* rp = (float*)(smem + RB + (t * 8 + w) * 8);
            s += rp[0]; q += rp[1];
        }
        float mu = s * (1.0f / 512.0f);
        float var = q * (1.0f / 512.0f) - mu * mu;
        float rs = rsqrtf(var + 1e-5f);
        float* sp = (float*)(smem + SB + t * 8);
        sp[0] = mu; sp[1] = rs;
    }
    __syncthreads();
    {
        float gm[4], bt[4];
#pragma unroll
        for (int fn = 0; fn < 4; fn++) { int c = n0w + fn * 16 + ln; gm[fn] = g1[c]; bt[fn] = be1[c]; }
#pragma unroll
        for (int fm = 0; fm < 2; fm++)
#pragma unroll
            for (int r = 0; r < 4; r++) {
                int row = fm * 16 + g * 4 + r;
                float* sp = (float*)(smem + SB + row * 8);
                float mu = sp[0], rs = sp[1];
#pragma unroll
                for (int fn = 0; fn < 4; fn++) {
                    int col = n0w + fn * 16 + ln;
                    float y = (acc[fm][fn][r] - mu) * rs * gm[fn] + bt[fn];
                    *(unsigned short*)(smem + hswz(row, col)) = f2bf(gelu(y));
                }
            }
    }
    __syncthreads();
    {
        int r = t >> 4, c0 = (t & 15) * 32;
        unsigned short* dst = h1 + (size_t)(lrow0 + r) * 512 + c0;
#pragma unroll
        for (int j = 0; j < 4; j++) {
            int gr = (c0 >> 3) + j;
            uint4 v = *(const uint4*)(smem + r * 1024 + ((gr ^ (r & 7)) << 4));
            *(uint4*)(dst + j * 8) = v;
        }
    }
}

// =========================================================================
// K23: GEMM2 + LN2 + GELU (in LDS) + GEMM3 + softmax + causal conv -> out
// No h2 round-trip. (512,4): measured no-spill (R13: WRITE == output).
// LDS: HBUF 32KB @0 | RB @32768 (2KB) | SB @34816 (256B)
// epilogue overlay of HBUF: LOGB @0 (32x272B), ABUF @8704 (32x544B)
// =========================================================================
#define SMEM_K23 35072
__global__ __launch_bounds__(NT, 4) void k23_fused(
    const unsigned short* __restrict__ h1, const float* __restrict__ a_bits,
    const float* __restrict__ b2, const float* __restrict__ g2, const float* __restrict__ be2,
    const float* __restrict__ b3, const unsigned short* __restrict__ wt,
    float* __restrict__ out, int rowoff) {
    __shared__ char smem[SMEM_K23];
    const int t = threadIdx.x;
    const int wave = t >> 6, lane = t & 63, g = lane >> 4, ln = lane & 15;
    const int lrow0 = blockIdx.x * BM;
    const int row0 = rowoff + lrow0;
    const int RB = 32768, SB = 34816;
    const unsigned short* wt2f = wt + 32768;
    const unsigned short* wt3f = wt + 294912;

    // stage h1 tile -> HBUF swizzled
    {
        int r = t >> 4, c0 = (t & 15) * 32;
        const unsigned short* src = h1 + (size_t)(lrow0 + r) * 512 + c0;
#pragma unroll
        for (int j = 0; j < 4; j++) {
            uint4 v = *(const uint4*)(src + j * 8);
            int gr = (c0 >> 3) + j;
            *(uint4*)(smem + r * 1024 + ((gr ^ (r & 7)) << 4)) = v;
        }
    }

    const int n0w = wave * 64;
    const unsigned short* bp[4];
#pragma unroll
    for (int fn = 0; fn < 4; fn++)
        bp[fn] = wt2f + ((size_t)(wave * 4 + fn) * 16 * 64 + lane) * 8;

    __syncthreads();

    // GEMM2 with depth-2 register pipeline on B
    f32x4 acc[2][4];
#pragma unroll
    for (int fm = 0; fm < 2; fm++)
#pragma unroll
        for (int fn = 0; fn < 4; fn++) acc[fm][fn] = (f32x4){0.f, 0.f, 0.f, 0.f};
    {
        s16x8 bcur[4], bnxt[4];
#pragma unroll
        for (int fn = 0; fn < 4; fn++) bcur[fn] = *(const s16x8*)(bp[fn]);
#pragma unroll
        for (int step = 0; step < 16; step++) {
            if (step < 15) {
#pragma unroll
                for (int fn = 0; fn < 4; fn++)
                    bnxt[fn] = *(const s16x8*)(bp[fn] + (size_t)(step + 1) * 512);
            }
            s16x8 af[2];
#pragma unroll
            for (int fm = 0; fm < 2; fm++)
                af[fm] = *(const s16x8*)(smem + hswz(fm * 16 + ln, step * 32 + g * 8));
#pragma unroll
            for (int fm = 0; fm < 2; fm++)
#pragma unroll
                for (int fn = 0; fn < 4; fn++) acc[fm][fn] = MFMA16(af[fm], bcur[fn], acc[fm][fn]);
#pragma unroll
            for (int fn = 0; fn < 4; fn++) bcur[fn] = bnxt[fn];
        }
    }

    // + bias, LN partials -> stats
    {
        float bb[4];
#pragma unroll
        for (int fn = 0; fn < 4; fn++) bb[fn] = b2[n0w + fn * 16 + ln];
#pragma unroll
        for (int fm = 0; fm < 2; fm++)
#pragma unroll
            for (int fn = 0; fn < 4; fn++)
#pragma unroll
                for (int r = 0; r < 4; r++) acc[fm][fn][r] += bb[fn];
    }
    ln_partials(acc, smem, RB, ln, g, wave);
    __syncthreads();   // all A-reads of HBUF done
    if (t < 32) {
        float s = 0.f, q = 0.f;
#pragma unroll
        for (int w = 0; w < 8; w++) {
            float* rp = (float*)(smem + RB + (t * 8 + w) * 8);
            s += rp[0]; q += rp[1];
        }
        float mu = s * (1.0f / 512.0f);
        float var = q * (1.0f / 512.0f) - mu * mu;
        float rs = rsqrtf(var + 1e-5f);
        float* sp = (float*)(smem + SB + t * 8);
        sp[0] = mu; sp[1] = rs;
    }
    __syncthreads();

    // LN2 apply + GELU -> HBUF swizzled (h2 lives only in LDS)
    {
        float gm[4], bt[4];
#pragma unroll
        for (int fn = 0; fn < 4; fn++) { int c = n0w + fn * 16 + ln; gm[fn] = g2[c]; bt[fn] = be2[c]; }
#pragma unroll
        for (int fm = 0; fm < 2; fm++)
#pragma unroll
            for (int r = 0; r < 4; r++) {
                int row = fm * 16 + g * 4 + r;
                float* sp = (float*)(smem + SB + row * 8);
                float mu = sp[0], rs = sp[1];
#pragma unroll
                for (int fn = 0; fn < 4; fn++) {
                    int col = n0w + fn * 16 + ln;
                    float y = (acc[fm][fn][r] - mu) * rs * gm[fn] + bt[fn];
                    *(unsigned short*)(smem + hswz(row, col)) = f2bf(gelu(y));
                }
            }
    }
    __syncthreads();

    // GEMM3: h2(32x512) @ W3(512x64); wave (mh,q) owns 16x16 tile; dual acc
    const int mh = wave >> 2, q = wave & 3;
    float b3v = b3[q * 16 + ln];
    const unsigned short* b3p = wt3f + ((size_t)q * 16 * 64 + lane) * 8;
    f32x4 acc3a = (f32x4){0.f, 0.f, 0.f, 0.f};
    f32x4 acc3b = (f32x4){0.f, 0.f, 0.f, 0.f};
#pragma unroll
    for (int ks = 0; ks < 16; ks += 2) {
        s16x8 bfr0 = *(const s16x8*)(b3p + (size_t)ks * 512);
        s16x8 bfr1 = *(const s16x8*)(b3p + (size_t)(ks + 1) * 512);
        s16x8 af0 = *(const s16x8*)(smem + hswz(mh * 16 + ln, ks * 32 + g * 8));
        s16x8 af1 = *(const s16x8*)(smem + hswz(mh * 16 + ln, (ks + 1) * 32 + g * 8));
        acc3a = MFMA16(af0, bfr0, acc3a);
        acc3b = MFMA16(af1, bfr1, acc3b);
    }
    __syncthreads();

    // logits + zero-padded a-tile (overlay HBUF, now dead)
    const int LOGB = 0, ABUF = 8704, LST = 272, AST = 544;
#pragma unroll
    for (int r = 0; r < 4; r++) {
        int row = mh * 16 + g * 4 + r;
        *(float*)(smem + LOGB + row * LST + (q * 16 + ln) * 4) = acc3a[r] + acc3b[r] + b3v;
    }
    {
        int r = t >> 4, c0 = (t & 15) * 4;
        float* ap = (float*)(smem + ABUF + r * AST);
        float4 z4 = {0.f, 0.f, 0.f, 0.f};
        *(float4*)(ap + c0) = z4;
        float4 av = *(const float4*)(a_bits + (size_t)(row0 + r) * 64 + c0);
        *(float4*)(ap + 64 + c0) = av;
    }
    __syncthreads();

    // softmax over 64 (16 thr/row)
    {
        int r = t >> 4, c0 = (t & 15) * 4;
        float* lp = (float*)(smem + LOGB + r * LST + c0 * 4);
        float4 v = *(float4*)lp;
        float mx = fmaxf(fmaxf(v.x, v.y), fmaxf(v.z, v.w));
#pragma unroll
        for (int d = 1; d < 16; d <<= 1) mx = fmaxf(mx, __shfl_xor(mx, d, 64));
        float e0 = __expf(v.x - mx), e1 = __expf(v.y - mx);
        float e2 = __expf(v.z - mx), e3 = __expf(v.w - mx);
        float s = e0 + e1 + e2 + e3;
#pragma unroll
        for (int d = 1; d < 16; d <<= 1) s += __shfl_xor(s, d, 64);
        float inv = 1.0f / s;
        float4 o; o.x = e0 * inv; o.y = e1 * inv; o.z = e2 * inv; o.w = e3 * inv;
        *(float4*)lp = o;
    }
    __syncthreads();

    // causal conv, 16 thr/row, 4 outs/thread, zero-padded sliding window
    {
        int r = t >> 4, i0 = (t & 15) * 4;
        const float* prow = (const float*)(smem + LOGB + r * LST);
        const float* apad = (const float*)(smem + ABUF + r * AST);
        float W[8];
        {
            float4 wa = *(const float4*)(apad + i0 + 60);
            float4 wb = *(const float4*)(apad + i0 + 64);
            W[0] = wa.x; W[1] = wa.y; W[2] = wa.z; W[3] = wa.w;
            W[4] = wb.x; W[5] = wb.y; W[6] = wb.z; W[7] = wb.w;
        }
        float o0 = 0.f, o1 = 0.f, o2 = 0.f, o3 = 0.f;
#pragma unroll
        for (int s4 = 0; s4 < 16; s4++) {
            float4 p4 = *(const float4*)(prow + 4 * s4);
            o0 = fmaf(p4.x, W[4], fmaf(p4.y, W[3], fmaf(p4.z, W[2], fmaf(p4.w, W[1], o0))));
            o1 = fmaf(p4.x, W[5], fmaf(p4.y, W[4], fmaf(p4.z, W[3], fmaf(p4.w, W[2], o1))));
            o2 = fmaf(p4.x, W[6], fmaf(p4.y, W[5], fmaf(p4.z, W[4], fmaf(p4.w, W[3], o2))));
            o3 = fmaf(p4.x, W[7], fmaf(p4.y, W[6], fmaf(p4.z, W[5], fmaf(p4.w, W[4], o3))));
            if (s4 < 15) {
                W[4] = W[0]; W[5] = W[1]; W[6] = W[2]; W[7] = W[3];
                float4 nw = *(const float4*)(apad + i0 + 56 - 4 * s4);
                W[0] = nw.x; W[1] = nw.y; W[2] = nw.z; W[3] = nw.w;
            }
        }
        float4 o; o.x = o0; o.y = o1; o.z = o2; o.w = o3;
        *(float4*)(out + (size_t)(row0 + r) * 64 + i0) = o;
    }
}

extern "C" void kernel_launch(void* const* d_in, const int* in_sizes, int n_in,
                              void* d_out, int out_size, void* d_ws, size_t ws_size,
                              hipStream_t stream) {
    const float* a_bits = (const float*)d_in[0];
    const float* shift  = (const float*)d_in[1];
    const float* W1  = (const float*)d_in[2];
    const float* b1  = (const float*)d_in[3];
    const float* g1  = (const float*)d_in[4];
    const float* be1 = (const float*)d_in[5];
    const float* W2  = (const float*)d_in[6];
    const float* b2  = (const float*)d_in[7];
    const float* g2  = (const float*)d_in[8];
    const float* be2 = (const float*)d_in[9];
    const float* W3  = (const float*)d_in[10];
    const float* b3  = (const float*)d_in[11];
    float* out = (float*)d_out;

    // workspace: wt [0,655360) | h1
    char* ws = (char*)d_ws;
    unsigned short* wt = (unsigned short*)ws;

    int CH = 1;
    while (CH < 32) {
        size_t need = 655360ull + 1024ull * (size_t)(BATCH / CH);
        if (need <= ws_size) break;
        CH *= 2;
    }
    const int chunk = BATCH / CH;
    unsigned short* h1 = (unsigned short*)(ws + 655360);

    weights_frag<<<640, 64, 0, stream>>>(W1, W2, W3, wt);
    for (int c = 0; c < CH; c++) {
        int rowoff = c * chunk;
        k1_gemm1<<<chunk / BM, NT, 0, stream>>>(shift, b1, g1, be1, wt, h1, rowoff);
        k23_fused<<<chunk / BM, NT, 0, stream>>>(h1, a_bits, b2, g2, be2, b3, wt, out, rowoff);
    }
}